// Round 5
// baseline (165.360 us; speedup 1.0000x reference)
//
#include <hip/hip_runtime.h>
#include <cmath>

#define T_TOKENS 16384
#define DIM 2048
#define HH 64
#define NG 4
#define EPG 16
#define NE 64
#define NJ 132
#define NJP 144          // padded to 9 n-tiles
#define NT 9
#define KCHUNK 512       // K per wave (4 waves cover 2048)
#define KSTEPS 16        // KCHUNK / 32
#define TAU 0.02f
#define KEPS 1.5e-3f

typedef __attribute__((ext_vector_type(8))) short bf16x8;
typedef __attribute__((ext_vector_type(4))) float f32x4;

// ws float-offsets
#define WF_FLOATS (64 * NT * 64 * 4)    // fragment-linear bf16 weights, 64 ksteps
#define SUM_OFF WF_FLOATS               // 128 floats: usage, rp
#define CNT_OFF (SUM_OFF + 128)
#define LIST_OFF (CNT_OFF + 4)          // int4 entries (16B aligned)

static __device__ inline unsigned bf16rne(float x) {
    unsigned u = __float_as_uint(x);
    return (u + 0x7FFFu + ((u >> 16) & 1u)) >> 16;
}
static __device__ inline unsigned pk2trunc(float a, float b) {
    return (__float_as_uint(a) >> 16) | (__float_as_uint(b) & 0xFFFF0000u);
}
static __device__ inline bf16x8 packA(float4 a, float4 b) {
    union { unsigned u[4]; bf16x8 v; } r;
    r.u[0] = pk2trunc(a.x, a.y); r.u[1] = pk2trunc(a.z, a.w);
    r.u[2] = pk2trunc(b.x, b.y); r.u[3] = pk2trunc(b.z, b.w);
    return r.v;
}

// Build fragment-linear bf16 weight buffer: [kstep 64][ntile 9][lane 64][16B]
// Block 0 also zeroes the global sums + flag counter.
__global__ void moe_prep(const float* __restrict__ Wg, const float* __restrict__ We,
                         const float* __restrict__ W1, float* __restrict__ ws,
                         float* __restrict__ sums, int* __restrict__ cnt) {
    int bid = blockIdx.x;                 // 576
    int kstep = bid / NT, nt = bid % NT;
    int lane = threadIdx.x;               // 64
    if (bid == 0) {
        sums[lane] = 0.f; sums[64 + lane] = 0.f;
        if (lane == 0) *cnt = 0;
    }
    int row = nt * 16 + (lane & 15);
    int k0 = kstep * 32 + (lane >> 4) * 8;
    const float* src = nullptr;
    if (row < HH)            src = W1 + (size_t)row * DIM;
    else if (row < HH + NG)  src = Wg + (size_t)(row - HH) * DIM;
    else if (row < NJ)       src = We + (size_t)(row - HH - NG) * DIM;
    unsigned r0 = 0, r1 = 0, r2 = 0, r3 = 0;
    if (src) {
        r0 = bf16rne(src[k0 + 0]) | (bf16rne(src[k0 + 1]) << 16);
        r1 = bf16rne(src[k0 + 2]) | (bf16rne(src[k0 + 3]) << 16);
        r2 = bf16rne(src[k0 + 4]) | (bf16rne(src[k0 + 5]) << 16);
        r3 = bf16rne(src[k0 + 6]) | (bf16rne(src[k0 + 7]) << 16);
    }
    ((uint4*)ws)[(size_t)(kstep * NT + nt) * 64 + lane] = make_uint4(r0, r1, r2, r3);
}

// Fused GEMM + epilogue: 1024 blocks x 256 threads; 16 tokens/block;
// wave w computes K-chunk [w*512,(w+1)*512) and ds_add's into the LDS logit tile.
__global__ __launch_bounds__(256, 4) void moe_fused(
    const float* __restrict__ x, const float* __restrict__ wfrag,
    const float* __restrict__ b1, const float* __restrict__ W2,
    const float* __restrict__ b2, const int* __restrict__ minE,
    const int* __restrict__ maxE, float* __restrict__ out,
    float* __restrict__ sums, int* __restrict__ cnt, int4* __restrict__ list) {
    __shared__ float slog[16][145];
    __shared__ float rp_s[16 * 17];
    __shared__ float sc_n1[16], sc_n2[16], sc_u2[16];
    __shared__ int   sc_e1[16], sc_e2[16], sc_g[16];
    __shared__ float s_usage[NE], s_rp[NE];

    const int tid = threadIdx.x;
    const int wave = tid >> 6, lane = tid & 63;
    const int l15 = lane & 15, lq = lane >> 4;
    const int T0 = blockIdx.x * 16;

    for (int i = tid; i < 16 * 145; i += 256) ((float*)slog)[i] = 0.f;
    if (tid < NE) { s_usage[tid] = 0.f; s_rp[tid] = 0.f; }
    __syncthreads();

    const int tokA = T0 + l15;
    const float4* xp = (const float4*)(x + (size_t)tokA * DIM + wave * KCHUNK + lq * 8);
    const bf16x8* wf = (const bf16x8*)wfrag + (size_t)(wave * KSTEPS) * NT * 64 + lane;

    f32x4 acc[NT];
    #pragma unroll
    for (int n = 0; n < NT; ++n) acc[n] = (f32x4){0.f, 0.f, 0.f, 0.f};

    float4 aA0 = xp[0], aA1 = xp[1];
    bf16x8 bA[NT], bB[NT];
    #pragma unroll
    for (int n = 0; n < NT; ++n) bA[n] = wf[n * 64];
    float4 aB0, aB1;

    #pragma unroll 2
    for (int t = 0; t < KSTEPS; t += 2) {
        const int t1 = (t + 1 < KSTEPS) ? t + 1 : t;
        aB0 = xp[t1 * 8]; aB1 = xp[t1 * 8 + 1];
        #pragma unroll
        for (int n = 0; n < NT; ++n) bB[n] = wf[(t1 * NT + n) * 64];
        bf16x8 af = packA(aA0, aA1);
        #pragma unroll
        for (int n = 0; n < NT; ++n)
            acc[n] = __builtin_amdgcn_mfma_f32_16x16x32_bf16(af, bA[n], acc[n], 0, 0, 0);

        const int t2 = (t + 2 < KSTEPS) ? t + 2 : t;
        aA0 = xp[t2 * 8]; aA1 = xp[t2 * 8 + 1];
        #pragma unroll
        for (int n = 0; n < NT; ++n) bA[n] = wf[(t2 * NT + n) * 64];
        af = packA(aB0, aB1);
        #pragma unroll
        for (int n = 0; n < NT; ++n)
            acc[n] = __builtin_amdgcn_mfma_f32_16x16x32_bf16(af, bB[n], acc[n], 0, 0, 0);
    }

    // C/D: col(n-dim) = l15, row(token) = lq*4 + r. Accumulate across waves in LDS.
    #pragma unroll
    for (int n = 0; n < NT; ++n)
        #pragma unroll
        for (int r = 0; r < 4; ++r)
            atomicAdd(&slog[lq * 4 + r][n * 16 + l15], acc[n][r]);
    __syncthreads();

    // per-token epilogue (16 tokens, lanes 0..15 of wave 0)
    if (tid < 16) {
        const int t = tid, tok = T0 + t;
        const float* o = slog[t];

        float z = b2[0];
        #pragma unroll 8
        for (int i = 0; i < HH; ++i) {
            float h = o[i] + b1[i];
            z = fmaf(W2[i], h > 0.f ? h : 0.f, z);
        }
        float c = 1.f / (1.f + expf(-z));
        int mx = maxE[0], mn = minE[0];
        float y = c * (float)mx;
        int k = (int)y; k = k < mn ? mn : (k > mx ? mx : k);
        int kl = (int)(y - KEPS); kl = kl < mn ? mn : (kl > mx ? mx : kl);
        int kh = (int)(y + KEPS); kh = kh < mn ? mn : (kh > mx ? mx : kh);
        bool flagK = (kl != kh);
        float u2 = (k >= 2) ? 1.f : 0.f;

        float gl[NG]; float gm = -INFINITY; int gi = 0;
        #pragma unroll
        for (int g = 0; g < NG; ++g) {
            gl[g] = o[HH + g];
            if (gl[g] > gm) { gm = gl[g]; gi = g; }
        }
        float g2 = -INFINITY;
        #pragma unroll
        for (int g = 0; g < NG; ++g) if (g != gi && gl[g] > g2) g2 = gl[g];
        bool flagG = (gm - g2) < TAU;
        float gsum = 0.f;
        #pragma unroll
        for (int g = 0; g < NG; ++g) gsum += expf(gl[g] - gm);
        float gp = 1.f / gsum;

        float el[EPG];
        #pragma unroll
        for (int j = 0; j < EPG; ++j) el[j] = o[HH + NG + gi * EPG + j];
        float e1 = -INFINITY, e2v = -INFINITY, e3v = -INFINITY; int i1 = 0, i2 = 0;
        #pragma unroll
        for (int j = 0; j < EPG; ++j) {
            float v = el[j];
            if (v > e1)       { e3v = e2v; e2v = e1; i2 = i1; e1 = v; i1 = j; }
            else if (v > e2v) { e3v = e2v; e2v = v; i2 = j; }
            else if (v > e3v) { e3v = v; }
        }
        bool flagE = ((e1 - e2v) < TAU) || (u2 > 0.f && (e2v - e3v) < TAU);

        float ep[EPG]; float es = 0.f;
        #pragma unroll
        for (int j = 0; j < EPG; ++j) { ep[j] = expf(el[j] - e1); es += ep[j]; }
        float inv = 1.f / es;
        #pragma unroll
        for (int j = 0; j < EPG; ++j) ep[j] *= inv;
        float v1 = ep[i1], v2 = ep[i2];
        float denom = v1 + v2 * u2;
        sc_n1[t] = v1 / denom; sc_n2[t] = v2 * u2 / denom; sc_u2[t] = u2;
        sc_e1[t] = gi * EPG + i1; sc_e2[t] = gi * EPG + i2; sc_g[t] = gi;
        #pragma unroll
        for (int j = 0; j < EPG; ++j) rp_s[t * 17 + j] = gp * ep[j];

        if (flagK || flagG || flagE) {
            int p = atomicAdd(cnt, 1);
            int fl = (flagG ? 1 : 0) | (flagE ? 2 : 0) | (flagK ? 4 : 0);
            list[p] = make_int4(tok, fl, (int)u2, 0);
        }
    }
    __syncthreads();

    float* outD = out;
    float* outC = out + (size_t)T_TOKENS * NE;
    float* outR = out + (size_t)2 * T_TOKENS * NE;
    for (int idx = tid; idx < 16 * NE; idx += 256) {
        int t = idx >> 6, e = idx & 63;
        int e1i = sc_e1[t], e2i = sc_e2[t];
        float disp = (e == e1i ? 1.f : 0.f) + (e == e2i ? sc_u2[t] : 0.f);
        float comb = (e == e1i ? sc_n1[t] : 0.f) + (e == e2i ? sc_n2[t] : 0.f);
        float rpv  = ((e >> 4) == sc_g[t]) ? rp_s[t * 17 + (e & 15)] : 0.f;
        size_t ob = (size_t)(T0 + t) * NE + e;
        outD[ob] = disp; outC[ob] = comb; outR[ob] = rpv;
        atomicAdd(&s_usage[e], disp);
        atomicAdd(&s_rp[e], rpv);
    }
    __syncthreads();
    if (tid < NE) {
        atomicAdd(&sums[tid], s_usage[tid]);
        atomicAdd(&sums[NE + tid], s_rp[tid]);
    }
}

// parallel fixup: one block (4 waves) per flagged token
__global__ __launch_bounds__(256, 4) void moe_fix(
    const float* __restrict__ x, const float* __restrict__ Wg,
    const float* __restrict__ We, const float* __restrict__ W1,
    const float* __restrict__ b1, const float* __restrict__ W2,
    const float* __restrict__ b2, const int* __restrict__ minE,
    const int* __restrict__ maxE, float* __restrict__ out,
    float* __restrict__ sums, const int* __restrict__ cnt,
    const int4* __restrict__ list) {
    __shared__ float gl_s[NG];
    __shared__ float h_s[HH];
    __shared__ float el_s[EPG];
    __shared__ float rp_row[EPG];
    __shared__ int   s_gi;
    __shared__ float s_u2, s_gp;
    __shared__ int   s_e1, s_e2;
    __shared__ float s_n1, s_n2;

    const int tid = threadIdx.x;
    const int wave = tid >> 6, lane = tid & 63;
    const int n = *cnt;

    for (int i = blockIdx.x; i < n; i += gridDim.x) {
        const int4 ent = list[i];
        const int tok = ent.x, fl = ent.y;
        const float u2_in = (float)ent.z;

        const float* xrow = x + (size_t)tok * DIM;
        float xr[32];
        #pragma unroll
        for (int m = 0; m < 32; ++m) xr[m] = xrow[lane + m * 64];

        auto dotf = [&](const float* w) -> float {
            float s = 0.f;
            #pragma unroll
            for (int m = 0; m < 32; ++m) s = fmaf(xr[m], w[lane + m * 64], s);
            #pragma unroll
            for (int off = 32; off; off >>= 1) s += __shfl_xor(s, off, 64);
            return s;
        };

        {
            float g = dotf(Wg + (size_t)wave * DIM);
            if (lane == 0) gl_s[wave] = g;
        }
        if (fl & 4) {
            for (int j = wave; j < HH; j += 4) {
                float hv = dotf(W1 + (size_t)j * DIM);
                if (lane == 0) h_s[j] = hv;
            }
        }
        __syncthreads();

        if (tid == 0) {
            float gm = -INFINITY; int gi = 0;
            #pragma unroll
            for (int g = 0; g < NG; ++g)
                if (gl_s[g] > gm) { gm = gl_s[g]; gi = g; }
            float gsum = 0.f;
            #pragma unroll
            for (int g = 0; g < NG; ++g) gsum += expf(gl_s[g] - gm);
            s_gp = 1.f / gsum;
            s_gi = gi;
            float u2 = u2_in;
            if (fl & 4) {
                float z = b2[0];
                for (int j = 0; j < HH; ++j) {
                    float h = h_s[j] + b1[j];
                    z = fmaf(W2[j], h > 0.f ? h : 0.f, z);
                }
                float c = 1.f / (1.f + expf(-z));
                int mx = maxE[0], mn = minE[0];
                int k = (int)(c * (float)mx);
                k = k < mn ? mn : (k > mx ? mx : k);
                u2 = (k >= 2) ? 1.f : 0.f;
            }
            s_u2 = u2;
        }
        __syncthreads();

        const int gi = s_gi;
        for (int j = wave; j < EPG; j += 4) {
            float e = dotf(We + (size_t)(gi * EPG + j) * DIM);
            if (lane == 0) el_s[j] = e;
        }
        __syncthreads();

        if (tid == 0) {
            float e1 = -INFINITY, e2v = -INFINITY; int i1 = 0, i2 = 0;
            #pragma unroll
            for (int j = 0; j < EPG; ++j) {
                float v = el_s[j];
                if (v > e1)       { e2v = e1; i2 = i1; e1 = v; i1 = j; }
                else if (v > e2v) { e2v = v; i2 = j; }
            }
            float es = 0.f;
            #pragma unroll
            for (int j = 0; j < EPG; ++j) {
                float e = expf(el_s[j] - e1);
                rp_row[j] = e;
                es += e;
            }
            float inv = 1.f / es;
            float gp = s_gp;
            #pragma unroll
            for (int j = 0; j < EPG; ++j) rp_row[j] *= inv * gp;
            float v1 = expf(el_s[i1] - e1) * inv;
            float v2 = expf(el_s[i2] - e1) * inv;
            float u2 = s_u2;
            float denom = v1 + v2 * u2;
            s_n1 = v1 / denom; s_n2 = v2 * u2 / denom;
            s_e1 = gi * EPG + i1; s_e2 = gi * EPG + i2;
        }
        __syncthreads();

        if (tid < NE) {
            const int e = tid;
            float u2 = s_u2;
            float newD = (e == s_e1 ? 1.f : 0.f) + (e == s_e2 ? u2 : 0.f);
            float newC = (e == s_e1 ? s_n1 : 0.f) + (e == s_e2 ? s_n2 : 0.f);
            float newR = ((e >> 4) == gi) ? rp_row[e & 15] : 0.f;
            size_t ob = (size_t)tok * NE + e;
            float oldD = out[ob];
            float oldR = out[(size_t)2 * T_TOKENS * NE + ob];
            out[ob] = newD;
            out[(size_t)T_TOKENS * NE + ob] = newC;
            out[(size_t)2 * T_TOKENS * NE + ob] = newR;
            float dD = newD - oldD, dR = newR - oldR;
            if (dD != 0.f) atomicAdd(&sums[e], dD);
            if (dR != 0.f) atomicAdd(&sums[NE + e], dR);
        }
        __syncthreads();
    }
}

__global__ void moe_finalize(const float* __restrict__ sums, float* __restrict__ out) {
    int l = threadIdx.x;
    float v = sums[l] * sums[NE + l];
    #pragma unroll
    for (int off = 32; off; off >>= 1) v += __shfl_down(v, off, 64);
    if (l == 0) {
        float N = (float)T_TOKENS;
        out[(size_t)3 * T_TOKENS * NE] = v * (float)NE / (N * N);
    }
}

extern "C" void kernel_launch(void* const* d_in, const int* in_sizes, int n_in,
                              void* d_out, int out_size, void* d_ws, size_t ws_size,
                              hipStream_t stream) {
    const float* x  = (const float*)d_in[0];
    const float* Wg = (const float*)d_in[1];
    const float* We = (const float*)d_in[2];
    const float* W1 = (const float*)d_in[3];
    const float* b1 = (const float*)d_in[4];
    const float* W2 = (const float*)d_in[5];
    const float* b2 = (const float*)d_in[6];
    const int* minE = (const int*)d_in[7];
    const int* maxE = (const int*)d_in[8];
    float* out = (float*)d_out;
    float* ws  = (float*)d_ws;

    float* wfrag = ws;
    float* sums  = ws + SUM_OFF;
    int*   cnt   = (int*)(ws + CNT_OFF);
    int4*  list  = (int4*)(ws + LIST_OFF);

    moe_prep<<<64 * NT, 64, 0, stream>>>(Wg, We, W1, wfrag, sums, cnt);
    moe_fused<<<T_TOKENS / 16, 256, 0, stream>>>(x, wfrag, b1, W2, b2, minE, maxE,
                                                 out, sums, cnt, list);
    moe_fix<<<2048, 256, 0, stream>>>(x, Wg, We, W1, b1, W2, b2, minE, maxE,
                                      out, sums, cnt, list);
    moe_finalize<<<1, 64, 0, stream>>>(sums, out);
}